// Round 11
// baseline (388.183 us; speedup 1.0000x reference)
//
#include <hip/hip_runtime.h>
#include <hip/hip_bf16.h>

// Glm4MoeExpertLayers: x[T,H] fp32, Wgu[E,2I,H] fp32, Wdn[E,H,I] fp32, expert_idx
//   gu = x @ Wgu[e]^T ; hidden = silu(gu[:, :I]) * gu[:, I:] ; out = hidden @ Wdn[e]^T
// T=16384 H=2048 I=1536.
// R11 = R10 (128^2 two-barrier gload_lds, conflict-free both-sides swizzle,
// high TLP) with:
//  1) 32x32x16 MFMA (2495 vs 2075 TF ceiling, half the instructions; swizzle
//     verified conflict-free under 8-lane service groups)
//  2) three cvt kernels fused into one (saves 2 launches)

namespace {

constexpr int T_ = 16384;
constexpr int H_ = 2048;
constexpr int I_ = 1536;

typedef short short8 __attribute__((ext_vector_type(8)));
typedef float f32x4 __attribute__((ext_vector_type(4)));
typedef float f32x16 __attribute__((ext_vector_type(16)));
typedef unsigned short ushort4v __attribute__((ext_vector_type(4)));

__device__ __forceinline__ unsigned short f2bf(float f) {
    union { float f; unsigned u; } v; v.f = f;
    return (unsigned short)((v.u + 0x7FFFu + ((v.u >> 16) & 1u)) >> 16);
}

typedef __attribute__((address_space(1))) const void gvoid;
typedef __attribute__((address_space(3))) void lvoid;
__device__ __forceinline__ void gload16(const void* g, void* l) {
    __builtin_amdgcn_global_load_lds((gvoid*)g, (lvoid*)l, 16, 0, 0);
}

// ---------------------------------------------------------------------------
// fused fp32->bf16 conversion of x, Wgu[e], Wdn[e]
// ---------------------------------------------------------------------------
__global__ void k_cvt_all(const float* __restrict__ x, const float* __restrict__ wgu,
                          const float* __restrict__ wdn, const int* __restrict__ eidx,
                          unsigned short* __restrict__ xb, unsigned short* __restrict__ wgub,
                          unsigned short* __restrict__ wdnb) {
    const int e = *eidx;
    const int n1 = T_ * H_ / 4;
    const int n2 = 2 * I_ * H_ / 4;
    const int n3 = H_ * I_ / 4;
    const int ntot = n1 + n2 + n3;
    const float* wgu_e = wgu + (size_t)e * (size_t)(2 * I_) * H_;
    const float* wdn_e = wdn + (size_t)e * (size_t)H_ * I_;
    const int stride = gridDim.x * blockDim.x;
    for (int i = blockIdx.x * blockDim.x + threadIdx.x; i < ntot; i += stride) {
        const float* src; unsigned short* dst; int j;
        if (i < n1)           { src = x;     dst = xb;   j = i; }
        else if (i < n1 + n2) { src = wgu_e; dst = wgub; j = i - n1; }
        else                  { src = wdn_e; dst = wdnb; j = i - n1 - n2; }
        f32x4 v = ((const f32x4*)src)[j];
        ushort4v h = { f2bf(v[0]), f2bf(v[1]), f2bf(v[2]), f2bf(v[3]) };
        ((ushort4v*)dst)[j] = h;
    }
}

// ---------------------------------------------------------------------------
// GEMM1 + SwiGLU: hidden[T,I](bf16) = silu(xb@Wg^T) * (xb@Wu^T)
// 256 thr (4 waves 2x2), tile 128x128, BK=64 over H, dual-B in-wave.
// 32x32x16 MFMA: per wave 2x2 frags of 32x32 (out 64x64), acc f32x16.
// LDS 3 x [128][8 slots of 16B] = 48 KiB, both-sides swizzled (slot ^= row&7).
// ---------------------------------------------------------------------------
__global__ __launch_bounds__(256, 2) void k_gemm1_swiglu(
    const unsigned short* __restrict__ xb, const unsigned short* __restrict__ wgub,
    unsigned short* __restrict__ hidden)
{
    __shared__ unsigned short lds[3 * 128 * 64];
    unsigned short* ldsA  = lds;
    unsigned short* ldsBg = lds + 128 * 64;
    unsigned short* ldsBu = lds + 2 * 128 * 64;

    const int tid  = threadIdx.x;
    const int lane = tid & 63;
    const int wv   = tid >> 6;
    const int wr   = wv >> 1, wc = wv & 1;

    const int nb = (blockIdx.x & 7) * 192 + (blockIdx.x >> 3);
    const int bx = nb % 12, by = nb / 12;
    const int m0 = by * 128;
    const int n0 = bx * 128;

    f32x16 accG[2][2], accU[2][2];
    #pragma unroll
    for (int a = 0; a < 2; ++a)
        #pragma unroll
        for (int b = 0; b < 2; ++b) { accG[a][b] = (f32x16)0.0f; accU[a][b] = (f32x16)0.0f; }

    const int drow = lane >> 3;                   // staging row (== row & 7)
    const int gcol = (((lane & 7) ^ drow) * 8);   // pre-swizzled source col (bf16)
    const int l31 = lane & 31;
    const int l5  = lane >> 5;                    // 0..1
    const int swr = lane & 7;                     // frag row & 7

    for (int k0 = 0; k0 < H_; k0 += 64) {
        __syncthreads();
        #pragma unroll
        for (int r = 0; r < 4; ++r) {
            const int row  = r * 32 + wv * 8 + drow;
            const int loff = r * 2048 + wv * 512;
            gload16(xb   + (size_t)(m0 + row)      * H_ + k0 + gcol, ldsA  + loff);
            gload16(wgub + (size_t)(n0 + row)      * H_ + k0 + gcol, ldsBg + loff);
            gload16(wgub + (size_t)(I_ + n0 + row) * H_ + k0 + gcol, ldsBu + loff);
        }
        __syncthreads();

        #pragma unroll
        for (int s = 0; s < 4; ++s) {             // 4 K-slices of 16
            const int sl = ((s * 2 + l5) ^ swr) * 8;   // physical 16B slot (ushorts)
            short8 af[2], bg[2], bu[2];
            #pragma unroll
            for (int fr = 0; fr < 2; ++fr)
                af[fr] = *(const short8*)(ldsA + (wr * 64 + fr * 32 + l31) * 64 + sl);
            #pragma unroll
            for (int fc = 0; fc < 2; ++fc) {
                bg[fc] = *(const short8*)(ldsBg + (wc * 64 + fc * 32 + l31) * 64 + sl);
                bu[fc] = *(const short8*)(ldsBu + (wc * 64 + fc * 32 + l31) * 64 + sl);
            }
            #pragma unroll
            for (int fr = 0; fr < 2; ++fr)
                #pragma unroll
                for (int fc = 0; fc < 2; ++fc) {
                    accG[fr][fc] = __builtin_amdgcn_mfma_f32_32x32x16_bf16(af[fr], bg[fc], accG[fr][fc], 0, 0, 0);
                    accU[fr][fc] = __builtin_amdgcn_mfma_f32_32x32x16_bf16(af[fr], bu[fc], accU[fr][fc], 0, 0, 0);
                }
        }
    }

    // epilogue: silu(gate)*up -> bf16 (32x32 C/D: row=(j&3)+8*(j>>2)+4*l5, col=l31)
    #pragma unroll
    for (int fr = 0; fr < 2; ++fr)
        #pragma unroll
        for (int fc = 0; fc < 2; ++fc)
            #pragma unroll
            for (int j = 0; j < 16; ++j) {
                const int row = m0 + wr * 64 + fr * 32 + (j & 3) + 8 * (j >> 2) + 4 * l5;
                const int col = n0 + wc * 64 + fc * 32 + l31;
                const float g = accG[fr][fc][j];
                const float u = accU[fr][fc][j];
                const float sgm = g / (1.0f + __expf(-g));
                hidden[(size_t)row * I_ + col] = f2bf(sgm * u);
            }
}

// ---------------------------------------------------------------------------
// GEMM2: out[T,H] fp32 = hidden(bf16) @ wdn_bf16^T. 128x128 tile, BK=64 over I.
// LDS 2 x 16 KiB = 32 KiB. 32x32x16 MFMA, 2x2 frags/wave.
// ---------------------------------------------------------------------------
__global__ __launch_bounds__(256, 2) void k_gemm2(
    const unsigned short* __restrict__ hidden, const unsigned short* __restrict__ wdnb,
    float* __restrict__ out)
{
    __shared__ unsigned short lds[2 * 128 * 64];
    unsigned short* ldsA = lds;
    unsigned short* ldsB = lds + 128 * 64;

    const int tid  = threadIdx.x;
    const int lane = tid & 63;
    const int wv   = tid >> 6;
    const int wr   = wv >> 1, wc = wv & 1;

    const int nb = (blockIdx.x & 7) * 256 + (blockIdx.x >> 3);
    const int bx = nb % 16, by = nb / 16;
    const int m0 = by * 128;
    const int n0 = bx * 128;

    f32x16 acc[2][2];
    #pragma unroll
    for (int a = 0; a < 2; ++a)
        #pragma unroll
        for (int b = 0; b < 2; ++b) acc[a][b] = (f32x16)0.0f;

    const int drow = lane >> 3;
    const int gcol = (((lane & 7) ^ drow) * 8);
    const int l31 = lane & 31;
    const int l5  = lane >> 5;
    const int swr = lane & 7;

    for (int k0 = 0; k0 < I_; k0 += 64) {
        __syncthreads();
        #pragma unroll
        for (int r = 0; r < 4; ++r) {
            const int row  = r * 32 + wv * 8 + drow;
            const int loff = r * 2048 + wv * 512;
            gload16(hidden + (size_t)(m0 + row) * I_ + k0 + gcol, ldsA + loff);
            gload16(wdnb   + (size_t)(n0 + row) * I_ + k0 + gcol, ldsB + loff);
        }
        __syncthreads();

        #pragma unroll
        for (int s = 0; s < 4; ++s) {
            const int sl = ((s * 2 + l5) ^ swr) * 8;
            short8 af[2], bw[2];
            #pragma unroll
            for (int fr = 0; fr < 2; ++fr)
                af[fr] = *(const short8*)(ldsA + (wr * 64 + fr * 32 + l31) * 64 + sl);
            #pragma unroll
            for (int fc = 0; fc < 2; ++fc)
                bw[fc] = *(const short8*)(ldsB + (wc * 64 + fc * 32 + l31) * 64 + sl);
            #pragma unroll
            for (int fr = 0; fr < 2; ++fr)
                #pragma unroll
                for (int fc = 0; fc < 2; ++fc)
                    acc[fr][fc] = __builtin_amdgcn_mfma_f32_32x32x16_bf16(af[fr], bw[fc], acc[fr][fc], 0, 0, 0);
        }
    }

    #pragma unroll
    for (int fr = 0; fr < 2; ++fr)
        #pragma unroll
        for (int fc = 0; fc < 2; ++fc)
            #pragma unroll
            for (int j = 0; j < 16; ++j) {
                const int row = m0 + wr * 64 + fr * 32 + (j & 3) + 8 * (j >> 2) + 4 * l5;
                const int col = n0 + wc * 64 + fc * 32 + l31;
                out[(size_t)row * H_ + col] = acc[fr][fc][j];
            }
}

} // namespace

extern "C" void kernel_launch(void* const* d_in, const int* in_sizes, int n_in,
                              void* d_out, int out_size, void* d_ws, size_t ws_size,
                              hipStream_t stream) {
    const float* x   = (const float*)d_in[0];   // [T, H]
    const float* wgu = (const float*)d_in[1];   // [E, 2I, H]
    const float* wdn = (const float*)d_in[2];   // [E, H, I]
    const int* eidx  = (const int*)d_in[3];     // [1]
    float* out = (float*)d_out;                 // [T, H]

    // d_out (134.2 MB fp32) temporarily holds xb (67.1 MB) — dead before k_gemm2
    // overwrites it. ws: hidden | wgu_bf16 | wdn_bf16 = 69.2 MB.
    unsigned short* xb     = (unsigned short*)d_out;
    unsigned short* hidden = (unsigned short*)d_ws;
    unsigned short* wgub   = (unsigned short*)((char*)d_ws + 50331648);
    unsigned short* wdnb   = (unsigned short*)((char*)d_ws + 62914560);

    k_cvt_all<<<2048, 256, 0, stream>>>(x, wgu, wdn, eidx, xb, wgub, wdnb);
    k_gemm1_swiglu<<<dim3((I_ / 128) * (T_ / 128)), 256, 0, stream>>>(xb, wgub, hidden);
    k_gemm2<<<dim3((H_ / 128) * (T_ / 128)), 256, 0, stream>>>(hidden, wdnb, out);
}